// Round 7
// baseline (1041.086 us; speedup 1.0000x reference)
//
#include <hip/hip_runtime.h>
#include <hip/hip_bf16.h>

#define BB 16
#define TT 1024
#define CC 2048
#define TS 32   // wkv scan segment length

typedef __attribute__((ext_vector_type(4))) float f32x4;
typedef __attribute__((ext_vector_type(8))) short bf16x8;

__device__ __forceinline__ unsigned short f2bf(float f) {
  union { float f; unsigned u; } x; x.f = f;
  unsigned r = x.u + 0x7fffu + ((x.u >> 16) & 1u);
  return (unsigned short)(r >> 16);
}
__device__ __forceinline__ float bf2f(unsigned short u) {
  union { unsigned u; float f; } x; x.u = ((unsigned)u) << 16;
  return x.f;
}

// fp32 -> bf16 (4-wide), grid-stride
__global__ void f2bf_kernel(const float* __restrict__ in,
                            unsigned short* __restrict__ out, int n4) {
  for (int i = blockIdx.x * blockDim.x + threadIdx.x; i < n4;
       i += gridDim.x * blockDim.x) {
    float4 v = ((const float4*)in)[i];
    ushort4 o;
    o.x = f2bf(v.x); o.y = f2bf(v.y); o.z = f2bf(v.z); o.w = f2bf(v.w);
    ((ushort4*)out)[i] = o;
  }
}

__global__ void zero_zbuf(unsigned short* __restrict__ z) {
  z[blockIdx.x * 256 + threadIdx.x] = 0;
}

// W'[n, c]      = m[c]   * W[n, c]   (c < 2048)
// W'[n, 2048+c] = (1-m[c])* W[n, c]
// n<2048: (Wk,mk); n<4096: (Wv,mv); else (Wr,mr)
__global__ void prep_w(const float* __restrict__ w0, const float* __restrict__ w1,
                       const float* __restrict__ w2,
                       const float* __restrict__ m0, const float* __restrict__ m1,
                       const float* __restrict__ m2,
                       unsigned short* __restrict__ Wf) {
  const int total = 6144 * 512;
  for (int g = blockIdx.x * blockDim.x + threadIdx.x; g < total;
       g += gridDim.x * blockDim.x) {
    int n = g >> 9;
    int c4 = (g & 511) << 2;
    int which = n >> 11, nl = n & 2047;
    const float* W  = which == 0 ? w0 : which == 1 ? w1 : w2;
    const float* Mx = which == 0 ? m0 : which == 1 ? m1 : m2;
    float4 wv = ((const float4*)(W + (size_t)nl * 2048))[c4 >> 2];
    float4 mv = ((const float4*)Mx)[c4 >> 2];
    ushort4 a, b;
    a.x = f2bf(wv.x * mv.x); a.y = f2bf(wv.y * mv.y);
    a.z = f2bf(wv.z * mv.z); a.w = f2bf(wv.w * mv.w);
    b.x = f2bf(wv.x * (1.f - mv.x)); b.y = f2bf(wv.y * (1.f - mv.y));
    b.z = f2bf(wv.z * (1.f - mv.z)); b.w = f2bf(wv.w * (1.f - mv.w));
    ((ushort4*)(Wf + (size_t)n * 4096))[c4 >> 2] = a;
    ((ushort4*)(Wf + (size_t)n * 4096 + 2048))[c4 >> 2] = b;
  }
}

// ---------------------------------------------------------------------------
// 256x256 GEMM, BK=64, 8 waves (2x4), 8-phase / 2-K-tiles-per-iter schedule,
// vmcnt(6) = 3 half-tiles in flight (m201 depth), sched_barrier(0) pins
// read-issue before each barrier. st-swizzle both-sides. XCD-bijective swz.
// FUSED=1: A row r sourced from xbf[gr] (cols<2048) / xbf[gr-1] or zero row
// (cols>=2048) — fused time-shift-mix; C split 3-way bf16 (k/v/r), local rows.
// FUSED=0: plain A (local rows), C fp32 with orow remap.
// ---------------------------------------------------------------------------
template<int FUSED>
__global__ __launch_bounds__(512, 2)
void gemm8p(const unsigned short* __restrict__ A,
            const unsigned short* __restrict__ Bw,
            void* __restrict__ C0, void* __restrict__ C1, void* __restrict__ C2,
            const unsigned short* __restrict__ zbuf,
            int N, int K, int tcShift, int t0) {
  __shared__ __align__(1024) unsigned char lds[131072];
  const int tid = threadIdx.x;
  const int lane = tid & 63;
  const int wid = tid >> 6;
  const int wr = wid >> 2;   // 0..1
  const int wc = wid & 3;    // 0..3

  const int nwg = gridDim.x;
  const int cpx = nwg >> 3;
  const int bid = blockIdx.x;
  const int wg = (bid & 7) * cpx + (bid >> 3);
  const int bcolN = N >> 8;
  const int brow = wg / bcolN;
  const int bcol = wg % bcolN;

  const int srow = tid >> 3;                                   // 0..63
  const int scolE = ((((tid & 7) * 16) ^ ((srow & 7) << 4)) >> 1);
  const int ldsWave = wid * 1024;
  const int rowB0 = ((srow >> 5) << 6) + (srow & 31);
  const int tcMask = (1 << tcShift) - 1;

  const int frow = lane & 15;
  const int fhi = (lane >> 4) << 4;
  const int fsw = (frow & 7) << 4;

// A slot(par,h): par*32768 + h*16384 (+ g*8192). B slots at +65536.
#define STA(par, h, g, kk) do {                                                \
    const unsigned short* _src;                                                \
    int _r = brow * 256 + (h) * 64 + (g) * 128 + srow;                         \
    if (FUSED) {                                                               \
      int _gr = ((_r >> tcShift) << 10) + t0 + (_r & tcMask);                  \
      if ((kk) < 2048) _src = A + (size_t)_gr * 2048 + (kk) + scolE;           \
      else {                                                                   \
        int _t = _gr & 1023;                                                   \
        _src = _t ? A + (size_t)(_gr - 1) * 2048 + ((kk) - 2048) + scolE       \
                  : zbuf + ((kk) - 2048) + scolE;                              \
      }                                                                        \
    } else {                                                                   \
      _src = A + (size_t)_r * K + (kk) + scolE;                                \
    }                                                                          \
    __builtin_amdgcn_global_load_lds(                                          \
        (const __attribute__((address_space(1))) void*)_src,                   \
        (__attribute__((address_space(3))) void*)(lds + (par) * 32768 +        \
            (h) * 16384 + (g) * 8192 + ldsWave), 16, 0, 0);                    \
  } while (0)

#define STB(par, h, g, kk)                                                     \
  __builtin_amdgcn_global_load_lds(                                            \
      (const __attribute__((address_space(1))) void*)(                         \
          Bw + (size_t)(bcol * 256 + rowB0 + (h) * 32 + (g) * 128) * K +       \
          (kk) + scolE),                                                       \
      (__attribute__((address_space(3))) void*)(lds + 65536 + (par) * 32768 +  \
          (h) * 16384 + (g) * 8192 + ldsWave), 16, 0, 0)

#define RD_A(par, h)                                                           \
  do { _Pragma("unroll") for (int m = 0; m < 4; ++m)                           \
       _Pragma("unroll") for (int kk = 0; kk < 2; ++kk)                        \
         af[m * 2 + kk] = *(const bf16x8*)(lds + (par) * 32768 +               \
             (h) * 16384 + (wr * 64 + m * 16 + frow) * 128 +                   \
             (((kk << 6) + fhi) ^ fsw));                                       \
  } while (0)
#define RD_B(par, h)                                                           \
  do { _Pragma("unroll") for (int n = 0; n < 2; ++n)                           \
       _Pragma("unroll") for (int kk = 0; kk < 2; ++kk)                        \
         bf[n * 2 + kk] = *(const bf16x8*)(lds + 65536 + (par) * 32768 +       \
             (h) * 16384 + (wc * 32 + n * 16 + frow) * 128 +                   \
             (((kk << 6) + fhi) ^ fsw));                                       \
  } while (0)

#define MFMA_Q(AM, AN)                                                         \
  do { __builtin_amdgcn_s_setprio(1);                                          \
       _Pragma("unroll") for (int m = 0; m < 4; ++m)                           \
       _Pragma("unroll") for (int n = 0; n < 2; ++n)                           \
       _Pragma("unroll") for (int kk = 0; kk < 2; ++kk)                        \
         acc[(AM) + m][(AN) + n] = __builtin_amdgcn_mfma_f32_16x16x32_bf16(    \
             af[m * 2 + kk], bf[n * 2 + kk], acc[(AM) + m][(AN) + n], 0, 0, 0);\
       __builtin_amdgcn_s_setprio(0); } while (0)

#define SBAR __builtin_amdgcn_sched_barrier(0)
#define BAR __builtin_amdgcn_s_barrier()
#define VMC6 asm volatile("s_waitcnt vmcnt(6)" ::: "memory")
#define VMC0 asm volatile("s_waitcnt vmcnt(0)" ::: "memory")

  const int NI = K >> 7;   // 2 K-tiles (BK=64) per iteration

  // Prologue: T0 complete (8 loads, oldest), then T1: Ah0, Bh1, Ah1 (6).
  // T1's Bh0 is staged at ph0 of iteration 0.
  STA(0, 0, 0, 0); STA(0, 0, 1, 0);
  STA(0, 1, 0, 0); STA(0, 1, 1, 0);
  STB(0, 0, 0, 0); STB(0, 0, 1, 0);
  STB(0, 1, 0, 0); STB(0, 1, 1, 0);
  STA(1, 0, 0, 64); STA(1, 0, 1, 64);
  STB(1, 1, 0, 64); STB(1, 1, 1, 64);
  STA(1, 1, 0, 64); STA(1, 1, 1, 64);
  VMC6;            // T0 fully landed; T1's 6 stay in flight
  BAR;

  f32x4 acc[8][4] = {};
  bf16x8 af[8], bf[4];

  for (int i = 0; i < NI; ++i) {
    const int kT1 = (i << 7) + 64;
    const int k2 = (i << 7) + 128;
    const int k3 = (i << 7) + 192;
    const bool st = (i + 1 < NI);

    // ph0: Q(mh0,nh0) of T0; stage T1's Bh0
    RD_A(0, 0); RD_B(0, 0);
    STB(1, 0, 0, kT1); STB(1, 0, 1, kT1);
    SBAR; BAR; MFMA_Q(0, 0); BAR;

    // ph1: Q(mh0,nh1); stage T0+2 Ah0
    RD_B(0, 1);
    if (st) { STA(0, 0, 0, k2); STA(0, 0, 1, k2); }
    SBAR; BAR; MFMA_Q(0, 2); BAR;

    // ph2: Q(mh1,nh1); stage T0+2 Bh1
    RD_A(0, 1);
    if (st) { STB(0, 1, 0, k2); STB(0, 1, 1, k2); }
    SBAR; BAR; MFMA_Q(4, 2); BAR;

    // ph3: Q(mh1,nh0) re-read Bh0; stage T0+2 Ah1; drain -> T1 fully valid
    RD_B(0, 0);
    if (st) { STA(0, 1, 0, k2); STA(0, 1, 1, k2); }
    SBAR; BAR; MFMA_Q(4, 0);
    if (st) { VMC6; } else { VMC0; }
    BAR;

    // ph4: T1 Q(mh0,nh0); stage T0+2 Bh0
    RD_A(1, 0); RD_B(1, 0);
    if (st) { STB(0, 0, 0, k2); STB(0, 0, 1, k2); }
    SBAR; BAR; MFMA_Q(0, 0); BAR;

    // ph5: Q(mh0,nh1); stage T1+2 Ah0
    RD_B(1, 1);
    if (st) { STA(1, 0, 0, k3); STA(1, 0, 1, k3); }
    SBAR; BAR; MFMA_Q(0, 2); BAR;

    // ph6: Q(mh1,nh1); stage T1+2 Bh1
    RD_A(1, 1);
    if (st) { STB(1, 1, 0, k3); STB(1, 1, 1, k3); }
    SBAR; BAR; MFMA_Q(4, 2); BAR;

    // ph7: Q(mh1,nh0) re-read Bh0; stage T1+2 Ah1; drain -> T0+2 fully valid
    RD_B(1, 0);
    if (st) { STA(1, 1, 0, k3); STA(1, 1, 1, k3); }
    SBAR; BAR; MFMA_Q(4, 0);
    if (st) { VMC6; }
    BAR;
  }
#undef STA
#undef STB
#undef RD_A
#undef RD_B
#undef MFMA_Q
#undef SBAR
#undef BAR
#undef VMC6
#undef VMC0

  const int crow0 = (lane >> 4) << 2;
  const int ccol = lane & 15;
  if (FUSED) {
    const int which = bcol >> 3;
    unsigned short* outp = which == 0 ? (unsigned short*)C0
                         : which == 1 ? (unsigned short*)C1
                                      : (unsigned short*)C2;
    const int colb = (bcol & 7) * 256 + wc * 64;
#pragma unroll
    for (int am = 0; am < 8; ++am)
#pragma unroll
      for (int an = 0; an < 4; ++an) {
        const int col = colb + (an >> 1) * 32 + (an & 1) * 16 + ccol;
#pragma unroll
        for (int j = 0; j < 4; ++j) {
          int r = brow * 256 + wr * 128 + (am >> 2) * 64 + (am & 3) * 16 +
                  crow0 + j;
          outp[(size_t)r * 2048 + col] = f2bf(acc[am][an][j]);
        }
      }
  } else {
    float* outp = (float*)C0;
#pragma unroll
    for (int am = 0; am < 8; ++am)
#pragma unroll
      for (int an = 0; an < 4; ++an) {
        const int col = bcol * 256 + wc * 64 + (an >> 1) * 32 + (an & 1) * 16 +
                        ccol;
#pragma unroll
        for (int j = 0; j < 4; ++j) {
          int r = brow * 256 + wr * 128 + (am >> 2) * 64 + (am & 3) * 16 +
                  crow0 + j;
          int orow = ((r >> tcShift) << 10) + t0 + (r & tcMask);
          outp[(size_t)orow * N + col] = acc[am][an][j];
        }
      }
  }
}

// ---------------------------------------------------------------------------
// WKV segmented scan (segment = TS steps), stabilized (aa,bb,pp) form.
// ---------------------------------------------------------------------------
__global__ void wkv_part(const float* __restrict__ time_decay,
                         const unsigned short* __restrict__ k,
                         const unsigned short* __restrict__ v,
                         float* __restrict__ paA, float* __restrict__ paB,
                         float* __restrict__ paP, int Tc) {
  int idx = blockIdx.x * blockDim.x + threadIdx.x;
  int c = idx & (CC - 1);
  int b = (idx >> 11) & (BB - 1);
  int s = idx >> 15;
  float w = -__expf(time_decay[c]);
  float aa = 0.f, bb = 0.f, pp = -1e38f;
  size_t base = ((size_t)b * Tc + s * TS) * CC + c;
  for (int t = 0; t < TS; ++t) {
    size_t off = base + (size_t)t * CC;
    float kt = bf2f(k[off]), vt = bf2f(v[off]);
    float ww2 = pp + w;
    float p2 = fmaxf(ww2, kt);
    float e1 = __expf(ww2 - p2), e2 = __expf(kt - p2);
    aa = e1 * aa + e2 * vt;
    bb = e1 * bb + e2;
    pp = p2;
  }
  paA[idx] = aa; paB[idx] = bb; paP[idx] = pp;
}

__global__ void wkv_comb(const float* __restrict__ time_decay,
                         const float* __restrict__ paA,
                         const float* __restrict__ paB,
                         const float* __restrict__ paP,
                         float* __restrict__ inA, float* __restrict__ inB,
                         float* __restrict__ inP,
                         float* __restrict__ state, int S, int t0) {
  int idx = blockIdx.x * blockDim.x + threadIdx.x;  // [0, BB*CC)
  int c = idx & (CC - 1);
  float w = -__expf(time_decay[c]);
  float wTs = w * (float)TS;
  float A, Bv, P;
  if (t0 == 0) { A = 0.f; Bv = 0.f; P = -1e38f; }
  else { A = state[idx]; Bv = state[32768 + idx]; P = state[65536 + idx]; }
  for (int s = 0; s < S; ++s) {
    size_t o = (size_t)s * 32768 + idx;
    inA[o] = A; inB[o] = Bv; inP[o] = P;
    float Pd = P + wTs;
    float Ps = paP[o];
    float Pn = fmaxf(Pd, Ps);
    float e1 = __expf(Pd - Pn), e2 = __expf(Ps - Pn);
    A = e1 * A + e2 * paA[o];
    Bv = e1 * Bv + e2 * paB[o];
    P = Pn;
  }
  state[idx] = A; state[32768 + idx] = Bv; state[65536 + idx] = P;
}

__global__ void wkv_out(const float* __restrict__ time_decay,
                        const float* __restrict__ time_first,
                        const unsigned short* __restrict__ k,
                        const unsigned short* __restrict__ v,
                        const unsigned short* __restrict__ r,
                        unsigned short* __restrict__ rwkv,
                        const float* __restrict__ inA,
                        const float* __restrict__ inB,
                        const float* __restrict__ inP, int Tc) {
  int idx = blockIdx.x * blockDim.x + threadIdx.x;
  int c = idx & (CC - 1);
  int b = (idx >> 11) & (BB - 1);
  int s = idx >> 15;
  float w = -__expf(time_decay[c]);
  float u = time_first[c];
  float aa = inA[idx], bb = inB[idx], pp = inP[idx];
  size_t base = ((size_t)b * Tc + s * TS) * CC + c;
  for (int t = 0; t < TS; ++t) {
    size_t off = base + (size_t)t * CC;
    float kt = bf2f(k[off]), vt = bf2f(v[off]);
    float ww = u + kt;
    float p = fmaxf(pp, ww);
    float e1 = __expf(pp - p), e2 = __expf(ww - p);
    float y = (e1 * aa + e2 * vt) / (e1 * bb + e2);
    float rr = bf2f(r[off]);
    float sr = 1.f / (1.f + __expf(-rr));
    rwkv[off] = f2bf(sr * y);
    float ww2 = pp + w;
    float p2 = fmaxf(ww2, kt);
    float e1b = __expf(ww2 - p2), e2b = __expf(kt - p2);
    aa = e1b * aa + e2b * vt;
    bb = e1b * bb + e2b;
    pp = p2;
  }
}

extern "C" void kernel_launch(void* const* d_in, const int* in_sizes, int n_in,
                              void* d_out, int out_size, void* d_ws,
                              size_t ws_size, hipStream_t stream) {
  const float* x          = (const float*)d_in[0];
  const float* time_decay = (const float*)d_in[1];
  const float* time_first = (const float*)d_in[2];
  const float* tmk        = (const float*)d_in[3];
  const float* tmv        = (const float*)d_in[4];
  const float* tmr        = (const float*)d_in[5];
  const float* key_w      = (const float*)d_in[6];
  const float* value_w    = (const float*)d_in[7];
  const float* rec_w      = (const float*)d_in[8];
  const float* out_w      = (const float*)d_in[9];
  float* out = (float*)d_out;

  const int MM = BB * TT;                           // 16384
  const size_t xbfBytes = (size_t)MM * CC * 2;      // 64 MB
  const size_t WfBytes  = (size_t)6144 * 4096 * 2;  // 48 MB
  const size_t woBytes  = (size_t)CC * CC * 2;      // 8 MB
  const size_t zBytes   = 4096 * 2;                 // 8 KB (zero row + pad)
  const size_t stBytes  = 3 * (size_t)BB * CC * 4;  // 384 KB
  const size_t fixed = xbfBytes + WfBytes + woBytes + zBytes + stBytes;

  // per-chunk: k,v,r,rwkv bf16 (8 B/elem) + scan bufs 6*S*32768*4
  int Tc = 1024;
  while (Tc > 32) {
    size_t chunkBytes = (size_t)BB * Tc * CC * 8 +
                        (size_t)(Tc / TS) * 6 * 32768 * 4;
    if (fixed + chunkBytes + 1024 <= ws_size) break;
    Tc >>= 1;
  }
  const int Mc = BB * Tc;
  const size_t NC = (size_t)Mc * CC;
  const int S = Tc / TS;

  char* p = (char*)d_ws;
  unsigned short* xbf = (unsigned short*)p; p += xbfBytes;
  unsigned short* Wf  = (unsigned short*)p; p += WfBytes;
  unsigned short* wobf= (unsigned short*)p; p += woBytes;
  unsigned short* zbuf= (unsigned short*)p; p += zBytes;
  float* state        = (float*)p;          p += stBytes;
  unsigned short* kbuf= (unsigned short*)p; p += NC * 2;
  unsigned short* vbuf= (unsigned short*)p; p += NC * 2;
  unsigned short* rbuf= (unsigned short*)p; p += NC * 2;
  unsigned short* rwkv= (unsigned short*)p; p += NC * 2;
  float* paA = (float*)p;
  float* paB = paA + (size_t)S * 32768;
  float* paP = paB + (size_t)S * 32768;
  float* inA = paP + (size_t)S * 32768;
  float* inB = inA + (size_t)S * 32768;
  float* inP = inB + (size_t)S * 32768;

  // one-time prep
  zero_zbuf<<<16, 256, 0, stream>>>(zbuf);
  f2bf_kernel<<<2048, 256, 0, stream>>>(x, xbf, MM * CC / 4);
  prep_w<<<2048, 256, 0, stream>>>(key_w, value_w, rec_w, tmk, tmv, tmr, Wf);
  f2bf_kernel<<<1024, 256, 0, stream>>>(out_w, wobf, CC * CC / 4);

  int tcShift = 0;
  while ((1 << tcShift) < Tc) ++tcShift;

  const int nwgF = (Mc / 256) * (6144 / 256);
  const int nwgO = (Mc / 256) * (CC / 256);

  for (int t0 = 0; t0 < TT; t0 += Tc) {
    // fused mix + {k,v,r} projections: [x | x_shift] (M x 4096) * W' (6144 x 4096)^T
    gemm8p<1><<<nwgF, 512, 0, stream>>>(xbf, Wf, kbuf, vbuf, rbuf, zbuf,
                                        6144, 4096, tcShift, t0);
    wkv_part<<<S * 128, 256, 0, stream>>>(time_decay, kbuf, vbuf,
                                          paA, paB, paP, Tc);
    wkv_comb<<<128, 256, 0, stream>>>(time_decay, paA, paB, paP,
                                      inA, inB, inP, state, S, t0);
    wkv_out<<<S * 128, 256, 0, stream>>>(time_decay, time_first, kbuf, vbuf,
                                         rbuf, rwkv, inA, inB, inP, Tc);
    gemm8p<0><<<nwgO, 512, 0, stream>>>(rwkv, wobf, out, nullptr, nullptr,
                                        zbuf, CC, CC, tcShift, t0);
  }
}

// Round 8
// 983.570 us; speedup vs baseline: 1.0585x; 1.0585x over previous
//
#include <hip/hip_runtime.h>
#include <hip/hip_bf16.h>

#define BB 16
#define TT 1024
#define CC 2048
#define TS 32   // wkv scan segment length

typedef __attribute__((ext_vector_type(4))) float f32x4;
typedef __attribute__((ext_vector_type(8))) short bf16x8;

__device__ __forceinline__ unsigned short f2bf(float f) {
  union { float f; unsigned u; } x; x.f = f;
  unsigned r = x.u + 0x7fffu + ((x.u >> 16) & 1u);
  return (unsigned short)(r >> 16);
}
__device__ __forceinline__ float bf2f(unsigned short u) {
  union { unsigned u; float f; } x; x.u = ((unsigned)u) << 16;
  return x.f;
}

__device__ __forceinline__ ushort4 mix4(float4 a, float4 b, float4 m) {
  ushort4 o;
  o.x = f2bf(a.x * m.x + b.x * (1.f - m.x));
  o.y = f2bf(a.y * m.y + b.y * (1.f - m.y));
  o.z = f2bf(a.z * m.z + b.z * (1.f - m.z));
  o.w = f2bf(a.w * m.w + b.w * (1.f - m.w));
  return o;
}

__global__ void f2bf_all(const float* __restrict__ w0, const float* __restrict__ w1,
                         const float* __restrict__ w2, const float* __restrict__ w3,
                         unsigned short* __restrict__ o0, unsigned short* __restrict__ o1,
                         unsigned short* __restrict__ o2, unsigned short* __restrict__ o3,
                         int n4each) {
  const float* ws[4] = {w0, w1, w2, w3};
  unsigned short* os[4] = {o0, o1, o2, o3};
  int total = 4 * n4each;
  for (int i = blockIdx.x * blockDim.x + threadIdx.x; i < total;
       i += gridDim.x * blockDim.x) {
    int seg = i / n4each, j = i - seg * n4each;
    float4 v = ((const float4*)ws[seg])[j];
    ushort4 o;
    o.x = f2bf(v.x); o.y = f2bf(v.y); o.z = f2bf(v.z); o.w = f2bf(v.w);
    ((ushort4*)os[seg])[j] = o;
  }
}

__global__ void mix_kernel(const float* __restrict__ x,
                           const float* __restrict__ tmk,
                           const float* __restrict__ tmv,
                           const float* __restrict__ tmr,
                           unsigned short* __restrict__ xk,
                           unsigned short* __restrict__ xv,
                           unsigned short* __restrict__ xr,
                           int t0, int Tc) {
  const int C4 = CC / 4;
  const int total = BB * Tc * C4;
  for (int g = blockIdx.x * blockDim.x + threadIdx.x; g < total;
       g += gridDim.x * blockDim.x) {
    int cg = g % C4;
    int lrow = g / C4;
    int tl = lrow % Tc;
    int b = lrow / Tc;
    int t = t0 + tl;
    size_t gidx = (size_t)(b * TT + t) * C4 + cg;
    float4 xc = ((const float4*)x)[gidx];
    float4 xp = make_float4(0.f, 0.f, 0.f, 0.f);
    if (t > 0) xp = ((const float4*)x)[gidx - C4];
    ((ushort4*)xk)[g] = mix4(xc, xp, ((const float4*)tmk)[cg]);
    ((ushort4*)xv)[g] = mix4(xc, xp, ((const float4*)tmv)[cg]);
    ((ushort4*)xr)[g] = mix4(xc, xp, ((const float4*)tmr)[cg]);
  }
}

// ---------------------------------------------------------------------------
// 256x256 GEMM, BK=64, 8 waves (2x4): A staged to LDS (dbuf 64KB, swizzled,
// 4x wave reuse), B loaded DIRECT to VGPRs (2x redundancy, 64B-coalesced,
// compiler-managed waits). One barrier + one counted vmcnt(8) per K-tile;
// B stays in flight across barriers. XCD-bijective block swizzle.
// C[orow,N] = A[M,K]*B[N,K]^T ; orow = (r>>tcShift)<<10 + t0 + (r&mask).
// ---------------------------------------------------------------------------
template<bool BF16OUT>
__global__ __launch_bounds__(512, 2)
void gemm_bd(const unsigned short* __restrict__ A,
             const unsigned short* __restrict__ Bw,
             void* __restrict__ Cv, int N, int K, int tcShift, int t0) {
  __shared__ __align__(1024) unsigned char lds[65536];
  const int tid = threadIdx.x;
  const int lane = tid & 63;
  const int wid = tid >> 6;
  const int wr = wid >> 2;   // 0..1 -> 128 rows
  const int wc = wid & 3;    // 0..3 -> 64 cols

  const int nwg = gridDim.x;
  const int cpx = nwg >> 3;
  const int bid = blockIdx.x;
  const int wg = (bid & 7) * cpx + (bid >> 3);
  const int bcolN = N >> 8;
  const int brow = wg / bcolN;
  const int bcol = wg % bcolN;

  const int srow = tid >> 3;                                   // 0..63
  const int scolE = ((((tid & 7) * 16) ^ ((srow & 7) << 4)) >> 1);
  const int frow = lane & 15;
  const int fk16 = (lane >> 4) << 4;   // byte offset of lane's k-group
  const int fsw = (frow & 7) << 4;

  const unsigned short* Arow = A + (size_t)(brow * 256 + srow) * K + scolE;
  const unsigned short* Bb =
      Bw + (size_t)(bcol * 256 + wc * 64 + frow) * K + ((lane >> 4) << 3);

  f32x4 acc[8][4] = {};
  bf16x8 bA[8], bB[8], af[4];

#define STAGEA(bufOff, tk) do {                                                \
    _Pragma("unroll") for (int g = 0; g < 4; ++g)                              \
      __builtin_amdgcn_global_load_lds(                                        \
          (const __attribute__((address_space(1))) void*)(                     \
              Arow + (size_t)(g * 64) * K + (tk)),                             \
          (__attribute__((address_space(3))) void*)(                           \
              lds + (bufOff) + g * 8192 + tid * 16), 16, 0, 0);                \
  } while (0)

#define BLOAD(dst, tk) do {                                                    \
    _Pragma("unroll") for (int n = 0; n < 4; ++n)                              \
    _Pragma("unroll") for (int kk = 0; kk < 2; ++kk)                           \
      dst[n * 2 + kk] =                                                        \
          *(const bf16x8*)(Bb + (size_t)(n * 16) * K + (tk) + kk * 32);        \
  } while (0)

#define COMPUTE(bufOff, bfr) do {                                              \
    _Pragma("unroll") for (int mq = 0; mq < 4; ++mq) {                         \
      _Pragma("unroll") for (int mi = 0; mi < 2; ++mi)                         \
      _Pragma("unroll") for (int kk = 0; kk < 2; ++kk) {                       \
        const int row = wr * 128 + (mq * 2 + mi) * 16 + frow;                  \
        af[mi * 2 + kk] = *(const bf16x8*)(lds + (bufOff) + row * 128 +        \
                            (((kk << 6) + fk16) ^ fsw));                       \
      }                                                                        \
      __builtin_amdgcn_s_setprio(1);                                           \
      _Pragma("unroll") for (int mi = 0; mi < 2; ++mi)                         \
      _Pragma("unroll") for (int n = 0; n < 4; ++n)                            \
      _Pragma("unroll") for (int kk = 0; kk < 2; ++kk)                         \
        acc[mq * 2 + mi][n] = __builtin_amdgcn_mfma_f32_16x16x32_bf16(         \
            af[mi * 2 + kk], bfr[n * 2 + kk], acc[mq * 2 + mi][n], 0, 0, 0);   \
      __builtin_amdgcn_s_setprio(0);                                           \
    } } while (0)

#define TILE_TOP do {                                                          \
    asm volatile("s_waitcnt vmcnt(8)" ::: "memory");                           \
    __builtin_amdgcn_sched_barrier(0);                                         \
    __builtin_amdgcn_s_barrier();                                              \
  } while (0)

  const int NT = K >> 6;

  STAGEA(0, 0);
  BLOAD(bA, 0);

  for (int t = 0; t < NT; t += 2) {
    // tile t: A in buf0, B in bA; prefetch t+1 into buf1/bB after the barrier
    TILE_TOP;
    if (t + 1 < NT) { STAGEA(32768, (t + 1) * 64); BLOAD(bB, (t + 1) * 64); }
    COMPUTE(0, bA);
    // tile t+1: A in buf1, B in bB; prefetch t+2 into buf0/bA
    TILE_TOP;
    if (t + 2 < NT) { STAGEA(0, (t + 2) * 64); BLOAD(bA, (t + 2) * 64); }
    COMPUTE(32768, bB);
  }
#undef STAGEA
#undef BLOAD
#undef COMPUTE
#undef TILE_TOP

  const int crow0 = (lane >> 4) << 2;
  const int ccol = lane & 15;
  const int tcMask = (1 << tcShift) - 1;
#pragma unroll
  for (int am = 0; am < 8; ++am)
#pragma unroll
    for (int an = 0; an < 4; ++an) {
      const int col = bcol * 256 + wc * 64 + an * 16 + ccol;
#pragma unroll
      for (int j = 0; j < 4; ++j) {
        int r = brow * 256 + wr * 128 + am * 16 + crow0 + j;
        int orow = ((r >> tcShift) << 10) + t0 + (r & tcMask);
        if (BF16OUT)
          ((unsigned short*)Cv)[(size_t)orow * N + col] = f2bf(acc[am][an][j]);
        else
          ((float*)Cv)[(size_t)orow * N + col] = acc[am][an][j];
      }
    }
}

// ---------------------------------------------------------------------------
// WKV segmented scan (segment = TS steps), stabilized (aa,bb,pp) form.
// ---------------------------------------------------------------------------
__global__ void wkv_part(const float* __restrict__ time_decay,
                         const unsigned short* __restrict__ k,
                         const unsigned short* __restrict__ v,
                         float* __restrict__ paA, float* __restrict__ paB,
                         float* __restrict__ paP, int Tc) {
  int idx = blockIdx.x * blockDim.x + threadIdx.x;
  int c = idx & (CC - 1);
  int b = (idx >> 11) & (BB - 1);
  int s = idx >> 15;
  float w = -__expf(time_decay[c]);
  float aa = 0.f, bb = 0.f, pp = -1e38f;
  size_t base = ((size_t)b * Tc + s * TS) * CC + c;
  for (int t = 0; t < TS; ++t) {
    size_t off = base + (size_t)t * CC;
    float kt = bf2f(k[off]), vt = bf2f(v[off]);
    float ww2 = pp + w;
    float p2 = fmaxf(ww2, kt);
    float e1 = __expf(ww2 - p2), e2 = __expf(kt - p2);
    aa = e1 * aa + e2 * vt;
    bb = e1 * bb + e2;
    pp = p2;
  }
  paA[idx] = aa; paB[idx] = bb; paP[idx] = pp;
}

__global__ void wkv_comb(const float* __restrict__ time_decay,
                         const float* __restrict__ paA,
                         const float* __restrict__ paB,
                         const float* __restrict__ paP,
                         float* __restrict__ inA, float* __restrict__ inB,
                         float* __restrict__ inP,
                         float* __restrict__ state, int S, int t0) {
  int idx = blockIdx.x * blockDim.x + threadIdx.x;  // [0, BB*CC)
  int c = idx & (CC - 1);
  float w = -__expf(time_decay[c]);
  float wTs = w * (float)TS;
  float A, Bv, P;
  if (t0 == 0) { A = 0.f; Bv = 0.f; P = -1e38f; }
  else { A = state[idx]; Bv = state[32768 + idx]; P = state[65536 + idx]; }
  for (int s = 0; s < S; ++s) {
    size_t o = (size_t)s * 32768 + idx;
    inA[o] = A; inB[o] = Bv; inP[o] = P;
    float Pd = P + wTs;
    float Ps = paP[o];
    float Pn = fmaxf(Pd, Ps);
    float e1 = __expf(Pd - Pn), e2 = __expf(Ps - Pn);
    A = e1 * A + e2 * paA[o];
    Bv = e1 * Bv + e2 * paB[o];
    P = Pn;
  }
  state[idx] = A; state[32768 + idx] = Bv; state[65536 + idx] = P;
}

__global__ void wkv_out(const float* __restrict__ time_decay,
                        const float* __restrict__ time_first,
                        const unsigned short* __restrict__ k,
                        const unsigned short* __restrict__ v,
                        const unsigned short* __restrict__ r,
                        unsigned short* __restrict__ rwkv,
                        const float* __restrict__ inA,
                        const float* __restrict__ inB,
                        const float* __restrict__ inP, int Tc) {
  int idx = blockIdx.x * blockDim.x + threadIdx.x;
  int c = idx & (CC - 1);
  int b = (idx >> 11) & (BB - 1);
  int s = idx >> 15;
  float w = -__expf(time_decay[c]);
  float u = time_first[c];
  float aa = inA[idx], bb = inB[idx], pp = inP[idx];
  size_t base = ((size_t)b * Tc + s * TS) * CC + c;
  for (int t = 0; t < TS; ++t) {
    size_t off = base + (size_t)t * CC;
    float kt = bf2f(k[off]), vt = bf2f(v[off]);
    float ww = u + kt;
    float p = fmaxf(pp, ww);
    float e1 = __expf(pp - p), e2 = __expf(ww - p);
    float y = (e1 * aa + e2 * vt) / (e1 * bb + e2);
    float rr = bf2f(r[off]);
    float sr = 1.f / (1.f + __expf(-rr));
    rwkv[off] = f2bf(sr * y);
    float ww2 = pp + w;
    float p2 = fmaxf(ww2, kt);
    float e1b = __expf(ww2 - p2), e2b = __expf(kt - p2);
    aa = e1b * aa + e2b * vt;
    bb = e1b * bb + e2b;
    pp = p2;
  }
}

extern "C" void kernel_launch(void* const* d_in, const int* in_sizes, int n_in,
                              void* d_out, int out_size, void* d_ws,
                              size_t ws_size, hipStream_t stream) {
  const float* x          = (const float*)d_in[0];
  const float* time_decay = (const float*)d_in[1];
  const float* time_first = (const float*)d_in[2];
  const float* tmk        = (const float*)d_in[3];
  const float* tmv        = (const float*)d_in[4];
  const float* tmr        = (const float*)d_in[5];
  const float* key_w      = (const float*)d_in[6];
  const float* value_w    = (const float*)d_in[7];
  const float* rec_w      = (const float*)d_in[8];
  const float* out_w      = (const float*)d_in[9];
  float* out = (float*)d_out;

  const size_t WW = (size_t)CC * CC;
  const size_t wtBytes = 4 * WW * 2;               // 32 MB
  const size_t stBytes = 3 * (size_t)BB * CC * 4;  // 384 KB

  // per-chunk = BB*Tc*CC * (xk2+xv2+xr2+rbuf2+kbuf2+vbuf2) = 12 B/elem
  int Tc = 1024;
  while (Tc > 32) {
    size_t chunkBytes = (size_t)BB * Tc * CC * 12;
    if (wtBytes + stBytes + chunkBytes + 1024 <= ws_size) break;
    Tc >>= 1;
  }
  const int Mc = BB * Tc;
  const size_t NC = (size_t)Mc * CC;
  const int S = Tc / TS;

  char* p = (char*)d_ws;
  unsigned short* wk  = (unsigned short*)p; p += WW * 2;
  unsigned short* wv  = (unsigned short*)p; p += WW * 2;
  unsigned short* wrr = (unsigned short*)p; p += WW * 2;
  unsigned short* wo  = (unsigned short*)p; p += WW * 2;
  float* state        = (float*)p;          p += stBytes;
  unsigned short* kbuf= (unsigned short*)p; p += NC * 2;
  unsigned short* vbuf= (unsigned short*)p; p += NC * 2;
  unsigned short* xk  = (unsigned short*)p; p += NC * 2;  // aliased: rwkv
  unsigned short* xv  = (unsigned short*)p; p += NC * 2;  // aliased: scan bufs
  unsigned short* xr  = (unsigned short*)p; p += NC * 2;
  unsigned short* rbuf= (unsigned short*)p; p += NC * 2;
  unsigned short* rwkv = xk;

  const size_t SBt = (size_t)S * 32768;
  float* paA = (float*)xv;
  float* paB = paA + SBt;
  float* paP = paB + SBt;
  float* inA = paP + SBt;
  float* inB = inA + SBt;
  float* inP = inB + SBt;

  f2bf_all<<<2048, 256, 0, stream>>>(key_w, value_w, rec_w, out_w,
                                     wk, wv, wrr, wo, (int)(WW / 4));

  int tcShift = 0;
  while ((1 << tcShift) < Tc) ++tcShift;

  const int nwg = (Mc / 256) * (CC / 256);
  int mixBlocks = (Mc * (CC / 4) + 255) / 256;
  if (mixBlocks > 4096) mixBlocks = 4096;

  for (int t0 = 0; t0 < TT; t0 += Tc) {
    mix_kernel<<<mixBlocks, 256, 0, stream>>>(x, tmk, tmv, tmr, xk, xv, xr,
                                              t0, Tc);
    gemm_bd<true><<<nwg, 512, 0, stream>>>(xk, wk, kbuf, CC, CC, 10, 0);
    gemm_bd<true><<<nwg, 512, 0, stream>>>(xv, wv, vbuf, CC, CC, 10, 0);
    wkv_part<<<S * 128, 256, 0, stream>>>(time_decay, kbuf, vbuf,
                                          paA, paB, paP, Tc);
    gemm_bd<true><<<nwg, 512, 0, stream>>>(xr, wrr, rbuf, CC, CC, 10, 0);
    wkv_comb<<<128, 256, 0, stream>>>(time_decay, paA, paB, paP,
                                      inA, inB, inP, state, S, t0);
    wkv_out<<<S * 128, 256, 0, stream>>>(time_decay, time_first, kbuf, vbuf,
                                         rbuf, rwkv, inA, inB, inP, Tc);
    gemm_bd<false><<<nwg, 512, 0, stream>>>(rwkv, wo, out, CC, CC,
                                            tcShift, t0);
  }
}

// Round 9
// 714.101 us; speedup vs baseline: 1.4579x; 1.3774x over previous
//
#include <hip/hip_runtime.h>
#include <hip/hip_bf16.h>

#define BB 16
#define TT 1024
#define CC 2048
#define TS 32   // wkv scan segment length

typedef __attribute__((ext_vector_type(4))) float f32x4;
typedef __attribute__((ext_vector_type(8))) short bf16x8;

__device__ __forceinline__ unsigned short f2bf(float f) {
  union { float f; unsigned u; } x; x.f = f;
  unsigned r = x.u + 0x7fffu + ((x.u >> 16) & 1u);
  return (unsigned short)(r >> 16);
}
__device__ __forceinline__ float bf2f(unsigned short u) {
  union { unsigned u; float f; } x; x.u = ((unsigned)u) << 16;
  return x.f;
}

__device__ __forceinline__ ushort4 mix4(float4 a, float4 b, float4 m) {
  ushort4 o;
  o.x = f2bf(a.x * m.x + b.x * (1.f - m.x));
  o.y = f2bf(a.y * m.y + b.y * (1.f - m.y));
  o.z = f2bf(a.z * m.z + b.z * (1.f - m.z));
  o.w = f2bf(a.w * m.w + b.w * (1.f - m.w));
  return o;
}

__global__ void f2bf_all(const float* __restrict__ w0, const float* __restrict__ w1,
                         const float* __restrict__ w2, const float* __restrict__ w3,
                         unsigned short* __restrict__ o0, unsigned short* __restrict__ o1,
                         unsigned short* __restrict__ o2, unsigned short* __restrict__ o3,
                         int n4each) {
  const float* ws[4] = {w0, w1, w2, w3};
  unsigned short* os[4] = {o0, o1, o2, o3};
  int total = 4 * n4each;
  for (int i = blockIdx.x * blockDim.x + threadIdx.x; i < total;
       i += gridDim.x * blockDim.x) {
    int seg = i / n4each, j = i - seg * n4each;
    float4 v = ((const float4*)ws[seg])[j];
    ushort4 o;
    o.x = f2bf(v.x); o.y = f2bf(v.y); o.z = f2bf(v.z); o.w = f2bf(v.w);
    ((ushort4*)os[seg])[j] = o;
  }
}

__global__ void mix_kernel(const float* __restrict__ x,
                           const float* __restrict__ tmk,
                           const float* __restrict__ tmv,
                           const float* __restrict__ tmr,
                           unsigned short* __restrict__ xk,
                           unsigned short* __restrict__ xv,
                           unsigned short* __restrict__ xr,
                           int t0, int Tc) {
  const int C4 = CC / 4;
  const int total = BB * Tc * C4;
  for (int g = blockIdx.x * blockDim.x + threadIdx.x; g < total;
       g += gridDim.x * blockDim.x) {
    int cg = g % C4;
    int lrow = g / C4;
    int tl = lrow % Tc;
    int b = lrow / Tc;
    int t = t0 + tl;
    size_t gidx = (size_t)(b * TT + t) * C4 + cg;
    float4 xc = ((const float4*)x)[gidx];
    float4 xp = make_float4(0.f, 0.f, 0.f, 0.f);
    if (t > 0) xp = ((const float4*)x)[gidx - C4];
    ((ushort4*)xk)[g] = mix4(xc, xp, ((const float4*)tmk)[cg]);
    ((ushort4*)xv)[g] = mix4(xc, xp, ((const float4*)tmv)[cg]);
    ((ushort4*)xr)[g] = mix4(xc, xp, ((const float4*)tmr)[cg]);
  }
}

// ---------------------------------------------------------------------------
// 256x256 GEMM, BK=64, 8 waves (2x4), 8-phase / 2-K-tiles-per-iter schedule.
// R9: B read ONCE per K-tile into bf[8] (reads/phase 12,4,8,0); template-
// faithful post-barrier {lgkmcnt(0); sched_barrier(0)} before each MFMA
// cluster. vmcnt(6)=3 half-tiles in flight, drains only at ph3/ph7.
// st-swizzle both-sides; XCD-bijective block swizzle.
// C[orow,N] = A[M,K]*B[N,K]^T ; orow = (r>>tcShift)<<10 + t0 + (r&mask).
// ---------------------------------------------------------------------------
template<bool BF16OUT>
__global__ __launch_bounds__(512, 2)
void gemm256(const unsigned short* __restrict__ A,
             const unsigned short* __restrict__ B,
             void* __restrict__ Cv, int N, int K, int tcShift, int t0) {
  __shared__ __align__(1024) unsigned char lds[131072];
  const int tid = threadIdx.x;
  const int lane = tid & 63;
  const int wid = tid >> 6;
  const int wr = wid >> 2;   // 0..1
  const int wc = wid & 3;    // 0..3

  const int nwg = gridDim.x;
  const int cpx = nwg >> 3;
  const int bid = blockIdx.x;
  const int wg = (bid & 7) * cpx + (bid >> 3);
  const int bcolN = N >> 8;
  const int brow = wg / bcolN;
  const int bcol = wg % bcolN;

  const unsigned short* Ag = A + (size_t)(brow * 256) * K;
  const unsigned short* Bg = B + (size_t)(bcol * 256) * K;

  const int srow = tid >> 3;                                   // 0..63
  const int scolE = ((((tid & 7) * 16) ^ ((srow & 7) << 4)) >> 1);
  const int ldsWave = wid * 1024;
  const int rowB0 = ((srow >> 5) << 6) + (srow & 31);

  const int frow = lane & 15;
  const int fhi = (lane >> 4) << 4;
  const int fsw = (frow & 7) << 4;

// A slot(par,h): par*32768 + h*16384 (+ g*8192). B slots at +65536.
#define STA(par, h, g, kk)                                                     \
  __builtin_amdgcn_global_load_lds(                                            \
      (const __attribute__((address_space(1))) void*)(                         \
          Ag + (size_t)(srow + (h) * 64 + (g) * 128) * K + (kk) + scolE),      \
      (__attribute__((address_space(3))) void*)(                               \
          lds + (par) * 32768 + (h) * 16384 + (g) * 8192 + ldsWave), 16, 0, 0)
#define STB(par, h, g, kk)                                                     \
  __builtin_amdgcn_global_load_lds(                                            \
      (const __attribute__((address_space(1))) void*)(                         \
          Bg + (size_t)(rowB0 + (h) * 32 + (g) * 128) * K + (kk) + scolE),     \
      (__attribute__((address_space(3))) void*)(lds + 65536 + (par) * 32768 +  \
          (h) * 16384 + (g) * 8192 + ldsWave), 16, 0, 0)

#define RD_A(par, h)                                                           \
  do { _Pragma("unroll") for (int m = 0; m < 4; ++m)                           \
       _Pragma("unroll") for (int kk = 0; kk < 2; ++kk)                        \
         af[m * 2 + kk] = *(const bf16x8*)(lds + (par) * 32768 +               \
             (h) * 16384 + (wr * 64 + m * 16 + frow) * 128 +                   \
             (((kk << 6) + fhi) ^ fsw));                                       \
  } while (0)
// bf[(h)*4 + n*2 + kk]
#define RD_B(par, h)                                                           \
  do { _Pragma("unroll") for (int n = 0; n < 2; ++n)                           \
       _Pragma("unroll") for (int kk = 0; kk < 2; ++kk)                        \
         bf[(h) * 4 + n * 2 + kk] = *(const bf16x8*)(lds + 65536 +             \
             (par) * 32768 + (h) * 16384 + (wc * 32 + n * 16 + frow) * 128 +   \
             (((kk << 6) + fhi) ^ fsw));                                       \
  } while (0)

// MFMA quadrant: acc rows AM.., acc cols AN.. using bf half HB (0 or 4)
#define MFMA_Q(AM, AN, HB)                                                     \
  do { __builtin_amdgcn_s_setprio(1);                                          \
       _Pragma("unroll") for (int m = 0; m < 4; ++m)                           \
       _Pragma("unroll") for (int n = 0; n < 2; ++n)                           \
       _Pragma("unroll") for (int kk = 0; kk < 2; ++kk)                        \
         acc[(AM) + m][(AN) + n] = __builtin_amdgcn_mfma_f32_16x16x32_bf16(    \
             af[m * 2 + kk], bf[(HB) + n * 2 + kk], acc[(AM) + m][(AN) + n],   \
             0, 0, 0);                                                         \
       __builtin_amdgcn_s_setprio(0); } while (0)

#define SBAR __builtin_amdgcn_sched_barrier(0)
#define BAR __builtin_amdgcn_s_barrier()
#define LGKM0 do { asm volatile("s_waitcnt lgkmcnt(0)" ::: "memory");          \
                   __builtin_amdgcn_sched_barrier(0); } while (0)
#define VMC6 asm volatile("s_waitcnt vmcnt(6)" ::: "memory")
#define VMC0 asm volatile("s_waitcnt vmcnt(0)" ::: "memory")

  const int NI = K >> 7;   // 2 K-tiles (BK=64) per iteration

  // Prologue: T0 complete (8 loads, oldest), then T1: Ah0, Bh1, Ah1 (6).
  // T1's Bh0 is staged at ph0 of iteration 0.
  STA(0, 0, 0, 0); STA(0, 0, 1, 0);
  STA(0, 1, 0, 0); STA(0, 1, 1, 0);
  STB(0, 0, 0, 0); STB(0, 0, 1, 0);
  STB(0, 1, 0, 0); STB(0, 1, 1, 0);
  STA(1, 0, 0, 64); STA(1, 0, 1, 64);
  STB(1, 1, 0, 64); STB(1, 1, 1, 64);
  STA(1, 1, 0, 64); STA(1, 1, 1, 64);
  VMC6;            // T0 fully landed; T1's 6 stay in flight
  BAR;

  f32x4 acc[8][4] = {};
  bf16x8 af[8], bf[8];

  for (int i = 0; i < NI; ++i) {
    const int kT1 = (i << 7) + 64;
    const int k2 = (i << 7) + 128;
    const int k3 = (i << 7) + 192;
    const bool st = (i + 1 < NI);

    // ph0: T0 Q(mh0,nh0); read A-h0 + B-h0; stage T1's Bh0
    RD_A(0, 0); RD_B(0, 0);
    STB(1, 0, 0, kT1); STB(1, 0, 1, kT1);
    SBAR; BAR; LGKM0; MFMA_Q(0, 0, 0); BAR;

    // ph1: Q(mh0,nh1); read B-h1; stage T0+2 Ah0
    RD_B(0, 1);
    if (st) { STA(0, 0, 0, k2); STA(0, 0, 1, k2); }
    SBAR; BAR; LGKM0; MFMA_Q(0, 2, 4); BAR;

    // ph2: Q(mh1,nh1); read A-h1; stage T0+2 Bh1
    RD_A(0, 1);
    if (st) { STB(0, 1, 0, k2); STB(0, 1, 1, k2); }
    SBAR; BAR; LGKM0; MFMA_Q(4, 2, 4); BAR;

    // ph3: Q(mh1,nh0) — bf[0..3] still live; stage T0+2 Ah1; drain
    if (st) { STA(0, 1, 0, k2); STA(0, 1, 1, k2); }
    SBAR; BAR; LGKM0; MFMA_Q(4, 0, 0);
    if (st) { VMC6; } else { VMC0; }
    BAR;

    // ph4: T1 Q(mh0,nh0); read A-h0 + B-h0; stage T0+2 Bh0
    RD_A(1, 0); RD_B(1, 0);
    if (st) { STB(0, 0, 0, k2); STB(0, 0, 1, k2); }
    SBAR; BAR; LGKM0; MFMA_Q(0, 0, 0); BAR;

    // ph5: Q(mh0,nh1); read B-h1; stage T1+2 Ah0
    RD_B(1, 1);
    if (st) { STA(1, 0, 0, k3); STA(1, 0, 1, k3); }
    SBAR; BAR; LGKM0; MFMA_Q(0, 2, 4); BAR;

    // ph6: Q(mh1,nh1); read A-h1; stage T1+2 Bh1
    RD_A(1, 1);
    if (st) { STB(1, 1, 0, k3); STB(1, 1, 1, k3); }
    SBAR; BAR; LGKM0; MFMA_Q(4, 2, 4); BAR;

    // ph7: Q(mh1,nh0); stage T1+2 Ah1; drain
    if (st) { STA(1, 1, 0, k3); STA(1, 1, 1, k3); }
    SBAR; BAR; LGKM0; MFMA_Q(4, 0, 0);
    if (st) { VMC6; }
    BAR;
  }
#undef STA
#undef STB
#undef RD_A
#undef RD_B
#undef MFMA_Q
#undef SBAR
#undef BAR
#undef LGKM0
#undef VMC6
#undef VMC0

  const int crow0 = (lane >> 4) << 2;
  const int ccol = lane & 15;
  const int tcMask = (1 << tcShift) - 1;
#pragma unroll
  for (int am = 0; am < 8; ++am)
#pragma unroll
    for (int an = 0; an < 4; ++an) {
      const int col = bcol * 256 + wc * 64 + (an >> 1) * 32 + (an & 1) * 16 + ccol;
#pragma unroll
      for (int j = 0; j < 4; ++j) {
        int r = brow * 256 + wr * 128 + (am >> 2) * 64 + (am & 3) * 16 + crow0 + j;
        int orow = ((r >> tcShift) << 10) + t0 + (r & tcMask);
        if (BF16OUT)
          ((unsigned short*)Cv)[(size_t)orow * N + col] = f2bf(acc[am][an][j]);
        else
          ((float*)Cv)[(size_t)orow * N + col] = acc[am][an][j];
      }
    }
}

// ---------------------------------------------------------------------------
// WKV segmented scan (segment = TS steps), stabilized (aa,bb,pp) form.
// ---------------------------------------------------------------------------
__global__ void wkv_part(const float* __restrict__ time_decay,
                         const unsigned short* __restrict__ k,
                         const unsigned short* __restrict__ v,
                         float* __restrict__ paA, float* __restrict__ paB,
                         float* __restrict__ paP, int Tc) {
  int idx = blockIdx.x * blockDim.x + threadIdx.x;
  int c = idx & (CC - 1);
  int b = (idx >> 11) & (BB - 1);
  int s = idx >> 15;
  float w = -__expf(time_decay[c]);
  float aa = 0.f, bb = 0.f, pp = -1e38f;
  size_t base = ((size_t)b * Tc + s * TS) * CC + c;
  for (int t = 0; t < TS; ++t) {
    size_t off = base + (size_t)t * CC;
    float kt = bf2f(k[off]), vt = bf2f(v[off]);
    float ww2 = pp + w;
    float p2 = fmaxf(ww2, kt);
    float e1 = __expf(ww2 - p2), e2 = __expf(kt - p2);
    aa = e1 * aa + e2 * vt;
    bb = e1 * bb + e2;
    pp = p2;
  }
  paA[idx] = aa; paB[idx] = bb; paP[idx] = pp;
}

__global__ void wkv_comb(const float* __restrict__ time_decay,
                         const float* __restrict__ paA,
                         const float* __restrict__ paB,
                         const float* __restrict__ paP,
                         float* __restrict__ inA, float* __restrict__ inB,
                         float* __restrict__ inP,
                         float* __restrict__ state, int S, int t0) {
  int idx = blockIdx.x * blockDim.x + threadIdx.x;  // [0, BB*CC)
  int c = idx & (CC - 1);
  float w = -__expf(time_decay[c]);
  float wTs = w * (float)TS;
  float A, Bv, P;
  if (t0 == 0) { A = 0.f; Bv = 0.f; P = -1e38f; }
  else { A = state[idx]; Bv = state[32768 + idx]; P = state[65536 + idx]; }
  for (int s = 0; s < S; ++s) {
    size_t o = (size_t)s * 32768 + idx;
    inA[o] = A; inB[o] = Bv; inP[o] = P;
    float Pd = P + wTs;
    float Ps = paP[o];
    float Pn = fmaxf(Pd, Ps);
    float e1 = __expf(Pd - Pn), e2 = __expf(Ps - Pn);
    A = e1 * A + e2 * paA[o];
    Bv = e1 * Bv + e2 * paB[o];
    P = Pn;
  }
  state[idx] = A; state[32768 + idx] = Bv; state[65536 + idx] = P;
}

__global__ void wkv_out(const float* __restrict__ time_decay,
                        const float* __restrict__ time_first,
                        const unsigned short* __restrict__ k,
                        const unsigned short* __restrict__ v,
                        const unsigned short* __restrict__ r,
                        unsigned short* __restrict__ rwkv,
                        const float* __restrict__ inA,
                        const float* __restrict__ inB,
                        const float* __restrict__ inP, int Tc) {
  int idx = blockIdx.x * blockDim.x + threadIdx.x;
  int c = idx & (CC - 1);
  int b = (idx >> 11) & (BB - 1);
  int s = idx >> 15;
  float w = -__expf(time_decay[c]);
  float u = time_first[c];
  float aa = inA[idx], bb = inB[idx], pp = inP[idx];
  size_t base = ((size_t)b * Tc + s * TS) * CC + c;
  for (int t = 0; t < TS; ++t) {
    size_t off = base + (size_t)t * CC;
    float kt = bf2f(k[off]), vt = bf2f(v[off]);
    float ww = u + kt;
    float p = fmaxf(pp, ww);
    float e1 = __expf(pp - p), e2 = __expf(ww - p);
    float y = (e1 * aa + e2 * vt) / (e1 * bb + e2);
    float rr = bf2f(r[off]);
    float sr = 1.f / (1.f + __expf(-rr));
    rwkv[off] = f2bf(sr * y);
    float ww2 = pp + w;
    float p2 = fmaxf(ww2, kt);
    float e1b = __expf(ww2 - p2), e2b = __expf(kt - p2);
    aa = e1b * aa + e2b * vt;
    bb = e1b * bb + e2b;
    pp = p2;
  }
}

extern "C" void kernel_launch(void* const* d_in, const int* in_sizes, int n_in,
                              void* d_out, int out_size, void* d_ws,
                              size_t ws_size, hipStream_t stream) {
  const float* x          = (const float*)d_in[0];
  const float* time_decay = (const float*)d_in[1];
  const float* time_first = (const float*)d_in[2];
  const float* tmk        = (const float*)d_in[3];
  const float* tmv        = (const float*)d_in[4];
  const float* tmr        = (const float*)d_in[5];
  const float* key_w      = (const float*)d_in[6];
  const float* value_w    = (const float*)d_in[7];
  const float* rec_w      = (const float*)d_in[8];
  const float* out_w      = (const float*)d_in[9];
  float* out = (float*)d_out;

  const size_t WW = (size_t)CC * CC;
  const size_t wtBytes = 4 * WW * 2;               // 32 MB
  const size_t stBytes = 3 * (size_t)BB * CC * 4;  // 384 KB

  // per-chunk = BB*Tc*CC * (xk2+xv2+xr2+rbuf2+kbuf2+vbuf2) = 12 B/elem
  int Tc = 1024;
  while (Tc > 32) {
    size_t chunkBytes = (size_t)BB * Tc * CC * 12;
    if (wtBytes + stBytes + chunkBytes + 1024 <= ws_size) break;
    Tc >>= 1;
  }
  const int Mc = BB * Tc;
  const size_t NC = (size_t)Mc * CC;
  const int S = Tc / TS;

  char* p = (char*)d_ws;
  unsigned short* wk  = (unsigned short*)p; p += WW * 2;
  unsigned short* wv  = (unsigned short*)p; p += WW * 2;
  unsigned short* wrr = (unsigned short*)p; p += WW * 2;
  unsigned short* wo  = (unsigned short*)p; p += WW * 2;
  float* state        = (float*)p;          p += stBytes;
  unsigned short* kbuf= (unsigned short*)p; p += NC * 2;
  unsigned short* vbuf= (unsigned short*)p; p += NC * 2;
  unsigned short* xk  = (unsigned short*)p; p += NC * 2;  // aliased: rwkv
  unsigned short* xv  = (unsigned short*)p; p += NC * 2;  // aliased: scan bufs
  unsigned short* xr  = (unsigned short*)p; p += NC * 2;
  unsigned short* rbuf= (unsigned short*)p; p += NC * 2;
  unsigned short* rwkv = xk;

  const size_t SBt = (size_t)S * 32768;
  float* paA = (float*)xv;
  float* paB = paA + SBt;
  float* paP = paB + SBt;
  float* inA = paP + SBt;
  float* inB = inA + SBt;
  float* inP = inB + SBt;

  f2bf_all<<<2048, 256, 0, stream>>>(key_w, value_w, rec_w, out_w,
                                     wk, wv, wrr, wo, (int)(WW / 4));

  int tcShift = 0;
  while ((1 << tcShift) < Tc) ++tcShift;

  const int nwg = (Mc / 256) * (CC / 256);
  int mixBlocks = (Mc * (CC / 4) + 255) / 256;
  if (mixBlocks > 4096) mixBlocks = 4096;

  for (int t0 = 0; t0 < TT; t0 += Tc) {
    mix_kernel<<<mixBlocks, 256, 0, stream>>>(x, tmk, tmv, tmr, xk, xv, xr,
                                              t0, Tc);
    gemm256<true><<<nwg, 512, 0, stream>>>(xk, wk, kbuf, CC, CC, 10, 0);
    gemm256<true><<<nwg, 512, 0, stream>>>(xv, wv, vbuf, CC, CC, 10, 0);
    wkv_part<<<S * 128, 256, 0, stream>>>(time_decay, kbuf, vbuf,
                                          paA, paB, paP, Tc);
    gemm256<true><<<nwg, 512, 0, stream>>>(xr, wrr, rbuf, CC, CC, 10, 0);
    wkv_comb<<<128, 256, 0, stream>>>(time_decay, paA, paB, paP,
                                      inA, inB, inP, state, S, t0);
    wkv_out<<<S * 128, 256, 0, stream>>>(time_decay, time_first, kbuf, vbuf,
                                         rbuf, rwkv, inA, inB, inP, Tc);
    gemm256<false><<<nwg, 512, 0, stream>>>(rwkv, wo, out, CC, CC,
                                            tcShift, t0);
  }
}